// Round 2
// 344.688 us; speedup vs baseline: 1.0395x; 1.0395x over previous
//
#include <hip/hip_runtime.h>
#include <hip/hip_bf16.h>
#include <stdint.h>

#define S_LEN 2048
#define DMODEL 1024
#define HEADS 16
#define DK 64
#define LDK 72   // padded stride for attn LDS tiles (144 B rows, 16B aligned)

// Q projection folds 1/sqrt(DK) * log2(e) so attention softmax is pure exp2.
#define QSCALE 0.18033688011112042f

typedef __attribute__((ext_vector_type(8))) short bf16x8;
typedef __attribute__((ext_vector_type(4))) float f32x4;

__device__ __forceinline__ unsigned short f2bf(float f) {
    union { float f; unsigned u; } c; c.f = f;
    unsigned u = c.u;
    u += 0x7fffu + ((u >> 16) & 1u);
    return (unsigned short)(u >> 16);
}

// pack two fp32 -> bf16x2 (RNE): 2x(bfe+add3) + v_perm
__device__ __forceinline__ unsigned pkbf(float a, float b) {
    union { float f; unsigned u; } ca, cb; ca.f = a; cb.f = b;
    unsigned ua = ca.u + (0x7fffu + ((ca.u >> 16) & 1u));
    unsigned ub = cb.u + (0x7fffu + ((cb.u >> 16) & 1u));
    return __builtin_amdgcn_perm(ub, ua, 0x07060302);  // [ub.hi16 : ua.hi16]
}

// single-instruction pack (gfx950): D.lo16 = bf16(a), D.hi16 = bf16(b), RNE.
__device__ __forceinline__ unsigned cvtpk(float a, float b) {
    unsigned r;
    asm("v_cvt_pk_bf16_f32 %0, %1, %2" : "=v"(r) : "v"(a), "v"(b));
    return r;
}

__device__ __forceinline__ void g2lds16(const unsigned short* g, unsigned short* l) {
    __builtin_amdgcn_global_load_lds((const __attribute__((address_space(1))) void*)g,
                                     (__attribute__((address_space(3))) void*)l, 16, 0, 0);
}

// ---------------------------------------------------------------------------
// fp32 -> bf16 convert pass. y selects tensor; 8 elems/thread.
// ---------------------------------------------------------------------------
__global__ __launch_bounds__(256) void convert_kernel(
    const float* __restrict__ q, const float* __restrict__ k, const float* __restrict__ v,
    const float* __restrict__ Wq, const float* __restrict__ Wk, const float* __restrict__ Wv,
    const float* __restrict__ Wo,
    unsigned short* __restrict__ qbf, unsigned short* __restrict__ kbf,
    unsigned short* __restrict__ vbf, unsigned short* __restrict__ wbf)
{
    const float* src; unsigned short* dst; int n8;
    const int y = blockIdx.y;
    if (y == 0)      { src = q;  dst = qbf;           n8 = 1048576; }
    else if (y == 1) { src = k;  dst = kbf;           n8 = 1048576; }
    else if (y == 2) { src = v;  dst = vbf;           n8 = 1048576; }
    else if (y == 3) { src = Wq; dst = wbf;           n8 = 131072; }
    else if (y == 4) { src = Wk; dst = wbf + 1048576; n8 = 131072; }
    else if (y == 5) { src = Wv; dst = wbf + 2097152; n8 = 131072; }
    else             { src = Wo; dst = wbf + 3145728; n8 = 131072; }
    int i = blockIdx.x * 256 + threadIdx.x;
    if (i >= n8) return;
    float4 f0 = ((const float4*)src)[(size_t)2 * i];
    float4 f1 = ((const float4*)src)[(size_t)2 * i + 1];
    union { unsigned u[4]; uint4 v; } o;
    o.u[0] = pkbf(f0.x, f0.y); o.u[1] = pkbf(f0.z, f0.w);
    o.u[2] = pkbf(f1.x, f1.y); o.u[3] = pkbf(f1.z, f1.w);
    *(uint4*)&dst[(size_t)8 * i] = o.v;
}

// ---------------------------------------------------------------------------
// bf16 GEMM Y = A @ B^T (m97 structure, global_load_lds staging, unpadded LDS)
// Proj variant: z selects {q,k,v}; scatter epilogue to head layouts.
// ---------------------------------------------------------------------------
__global__ __launch_bounds__(256) void proj_gemm_kernel(
    const unsigned short* __restrict__ qbf, const unsigned short* __restrict__ kbf,
    const unsigned short* __restrict__ vbf, const unsigned short* __restrict__ wbf,
    unsigned short* __restrict__ qh, unsigned short* __restrict__ kh,
    unsigned short* __restrict__ vh_t)
{
    const unsigned short* A; const unsigned short* Bm; unsigned short* Y;
    const int z = blockIdx.z;
    if (z == 0)      { A = qbf; Bm = wbf;           Y = qh;   }
    else if (z == 1) { A = kbf; Bm = wbf + 1048576; Y = kh;   }
    else             { A = vbf; Bm = wbf + 2097152; Y = vh_t; }

    __shared__ unsigned short sA[128 * 64];
    __shared__ unsigned short sB[128 * 64];

    const int t    = threadIdx.x;
    const int lane = t & 63;
    const int wid  = t >> 6;
    const int wrow = (wid >> 1) * 64;
    const int wcol = (wid & 1) * 64;
    const int m0   = blockIdx.x * 128;
    const int n0   = blockIdx.y * 128;
    const int lrow = lane & 15;
    const int quad = lane >> 4;
    const int lk   = quad * 8;

    const unsigned short* gA = A + (size_t)(m0 + wid * 32 + (lane >> 3)) * 1024 + (lane & 7) * 8;
    const unsigned short* gB = Bm + (size_t)(n0 + wid * 32 + (lane >> 3)) * 1024 + (lane & 7) * 8;
    unsigned short* lA = sA + wid * 2048;
    unsigned short* lB = sB + wid * 2048;

    f32x4 acc[4][4];
    for (int i = 0; i < 4; i++) for (int j = 0; j < 4; j++) acc[i][j] = (f32x4){0.f, 0.f, 0.f, 0.f};

    for (int kb = 0; kb < 1024; kb += 64) {
        __syncthreads();
        for (int it = 0; it < 4; ++it) {
            g2lds16(gA + (size_t)it * 8 * 1024, lA + it * 512);
            g2lds16(gB + (size_t)it * 8 * 1024, lB + it * 512);
        }
        gA += 64; gB += 64;
        __syncthreads();
        for (int kk = 0; kk < 64; kk += 32) {
            bf16x8 a[4], b[4];
            for (int i = 0; i < 4; i++) a[i] = *(const bf16x8*)&sA[(wrow + i * 16 + lrow) * 64 + kk + lk];
            for (int j = 0; j < 4; j++) b[j] = *(const bf16x8*)&sB[(wcol + j * 16 + lrow) * 64 + kk + lk];
            for (int i = 0; i < 4; i++)
                for (int j = 0; j < 4; j++)
                    acc[i][j] = __builtin_amdgcn_mfma_f32_16x16x32_bf16(a[i], b[j], acc[i][j], 0, 0, 0);
        }
    }

    const float scale = (z == 0) ? QSCALE : 1.0f;
    for (int i = 0; i < 4; i++) {
        int grow = m0 + wrow + i * 16 + quad * 4;
        for (int j = 0; j < 4; j++) {
            int gcol = n0 + wcol + j * 16 + lrow;
            int h = gcol >> 6, d = gcol & 63;
            for (int r = 0; r < 4; r++) {
                int row = grow + r;
                int b_ = row >> 11;
                int s_ = row & 2047;
                unsigned short val = f2bf(acc[i][j][r] * scale);
                if (z == 2)
                    Y[(((size_t)(b_ * HEADS + h) * DK) + d) * S_LEN + s_] = val;
                else
                    Y[(((size_t)(b_ * HEADS + h) * S_LEN) + s_) * DK + d] = val;
            }
        }
    }
}

// Out projection: out = ctx(bf16) @ Wo^T, fp32 row-major output.
__global__ __launch_bounds__(256) void outproj_gemm_kernel(
    const unsigned short* __restrict__ ctx, const unsigned short* __restrict__ wobf,
    float* __restrict__ out)
{
    __shared__ unsigned short sA[128 * 64];
    __shared__ unsigned short sB[128 * 64];

    const int t    = threadIdx.x;
    const int lane = t & 63;
    const int wid  = t >> 6;
    const int wrow = (wid >> 1) * 64;
    const int wcol = (wid & 1) * 64;
    const int m0   = blockIdx.x * 128;
    const int n0   = blockIdx.y * 128;
    const int lrow = lane & 15;
    const int quad = lane >> 4;
    const int lk   = quad * 8;

    const unsigned short* gA = ctx  + (size_t)(m0 + wid * 32 + (lane >> 3)) * 1024 + (lane & 7) * 8;
    const unsigned short* gB = wobf + (size_t)(n0 + wid * 32 + (lane >> 3)) * 1024 + (lane & 7) * 8;
    unsigned short* lA = sA + wid * 2048;
    unsigned short* lB = sB + wid * 2048;

    f32x4 acc[4][4];
    for (int i = 0; i < 4; i++) for (int j = 0; j < 4; j++) acc[i][j] = (f32x4){0.f, 0.f, 0.f, 0.f};

    for (int kb = 0; kb < 1024; kb += 64) {
        __syncthreads();
        for (int it = 0; it < 4; ++it) {
            g2lds16(gA + (size_t)it * 8 * 1024, lA + it * 512);
            g2lds16(gB + (size_t)it * 8 * 1024, lB + it * 512);
        }
        gA += 64; gB += 64;
        __syncthreads();
        for (int kk = 0; kk < 64; kk += 32) {
            bf16x8 a[4], b[4];
            for (int i = 0; i < 4; i++) a[i] = *(const bf16x8*)&sA[(wrow + i * 16 + lrow) * 64 + kk + lk];
            for (int j = 0; j < 4; j++) b[j] = *(const bf16x8*)&sB[(wcol + j * 16 + lrow) * 64 + kk + lk];
            for (int i = 0; i < 4; i++)
                for (int j = 0; j < 4; j++)
                    acc[i][j] = __builtin_amdgcn_mfma_f32_16x16x32_bf16(a[i], b[j], acc[i][j], 0, 0, 0);
        }
    }

    for (int i = 0; i < 4; i++) {
        int grow = m0 + wrow + i * 16 + quad * 4;
        for (int j = 0; j < 4; j++) {
            int gcol = n0 + wcol + j * 16 + lrow;
            for (int r = 0; r < 4; r++)
                out[(size_t)(grow + r) * DMODEL + gcol] = acc[i][j][r];
        }
    }
}

// ---------------------------------------------------------------------------
// Flash attention, causal — transposed-S, fixed-base exp2 softmax.
// PAIRED q-tiles (qt, 15-qt): uniform 34 k-tiles/block.
// R1: XCD-bijective swizzle + async-STAGE prefetch (T14) + v_cvt_pk_bf16_f32
//     P-pack + deferred row-sum reduce + setprio around MFMA (T5).
// ---------------------------------------------------------------------------
__global__ __launch_bounds__(256) void attn_kernel(
    const unsigned short* __restrict__ qh, const unsigned short* __restrict__ kh,
    const unsigned short* __restrict__ vh_t, unsigned short* __restrict__ ctx)
{
    __shared__ unsigned short sK[64 * LDK];
    __shared__ unsigned short sVt[64 * LDK];
    __shared__ unsigned short sPT[4][32 * LDK];   // per-wave [query][key]

    const int t    = threadIdx.x;
    const int lane = t & 63;
    const int wid  = t >> 6;
    // bijective XCD swizzle (nwg=512, 512%8==0): hw linear id -> work id so
    // all 8 q-blocks of one bh land on one XCD (K/V become L2-resident).
    const int lin  = (int)(blockIdx.y * gridDim.x + blockIdx.x);
    const int wlin = (lin & 7) * 64 + (lin >> 3);
    const int qx   = wlin & 7;
    const int bh   = wlin >> 3;
    const size_t base = (size_t)bh * S_LEN * DK;
    const int lrow = lane & 15;
    const int quad = lane >> 4;
    const int b_ = bh >> 4, h_ = bh & 15;
    unsigned short* myPT = &sPT[wid][0];

    // staging geometry (fixed per thread; two halves 32 rows apart)
    const int sr0 = t >> 3;            // 0..31
    const int sc0 = (t & 7) * 8;       // 0..56 shorts
    const unsigned short* gK = kh + base;     // [key][d]
    const unsigned short* gV = vh_t + base;   // [d][key]

    for (int pass = 0; pass < 2; ++pass) {
        const int qt = pass ? (15 - qx) : qx;
        const int q0 = qt * 128;
        const int qw0 = q0 + wid * 32;   // this wave's first query row

        // Q fragments -> registers (reused across all k-tiles of this pass)
        bf16x8 qreg[2][2];
        for (int nf = 0; nf < 2; ++nf)
            for (int h = 0; h < 2; ++h)
                qreg[nf][h] = *(const bf16x8*)&qh[base + (size_t)(qw0 + nf * 16 + lrow) * DK + h * 32 + quad * 8];

        f32x4 o[4][2];   // [mf(d)][nf(query)]
        for (int mf = 0; mf < 4; mf++) for (int nf = 0; nf < 2; nf++) o[mf][nf] = (f32x4){0.f, 0.f, 0.f, 0.f};
        float lstat[2] = { 0.f, 0.f };   // lane-local partial row sums

        const int ntiles = q0 / 64 + 2;   // keys < q0+128

        // prologue prefetch for kt=0 (T14: loads decoupled from LDS write)
        uint4 rK0 = *(const uint4*)&gK[(size_t)sr0 * DK + sc0];
        uint4 rK1 = *(const uint4*)&gK[(size_t)(sr0 + 32) * DK + sc0];
        uint4 rV0 = *(const uint4*)&gV[(size_t)sr0 * S_LEN + sc0];
        uint4 rV1 = *(const uint4*)&gV[(size_t)(sr0 + 32) * S_LEN + sc0];

        for (int kt = 0; kt < ntiles; ++kt) {
            const int k0 = kt * 64;
            __syncthreads();   // protect sK/sVt from previous tile's readers
            *(uint4*)&sK [sr0 * LDK + sc0]        = rK0;
            *(uint4*)&sK [(sr0 + 32) * LDK + sc0] = rK1;
            *(uint4*)&sVt[sr0 * LDK + sc0]        = rV0;
            *(uint4*)&sVt[(sr0 + 32) * LDK + sc0] = rV1;
            if (kt + 1 < ntiles) {   // issue next tile's loads; land under compute
                const int kn = k0 + 64;
                rK0 = *(const uint4*)&gK[(size_t)(kn + sr0) * DK + sc0];
                rK1 = *(const uint4*)&gK[(size_t)(kn + sr0 + 32) * DK + sc0];
                rV0 = *(const uint4*)&gV[(size_t)sr0 * S_LEN + kn + sc0];
                rV1 = *(const uint4*)&gV[(size_t)(sr0 + 32) * S_LEN + kn + sc0];
            }
            __syncthreads();

            if (k0 > qw0 + 31) continue;   // fully masked for this wave

            // S^T = K Q^T  (Q pre-scaled by 1/sqrt(DK)*log2e)
            f32x4 st[4][2];
            for (int mf = 0; mf < 4; mf++) for (int nf = 0; nf < 2; nf++) st[mf][nf] = (f32x4){0.f, 0.f, 0.f, 0.f};
            for (int h = 0; h < 2; ++h) {
                bf16x8 kf[4];
                for (int mf = 0; mf < 4; mf++)
                    kf[mf] = *(const bf16x8*)&sK[(mf * 16 + lrow) * LDK + h * 32 + quad * 8];
                __builtin_amdgcn_s_setprio(1);
                for (int mf = 0; mf < 4; mf++)
                    for (int nf = 0; nf < 2; nf++)
                        st[mf][nf] = __builtin_amdgcn_mfma_f32_16x16x32_bf16(kf[mf], qreg[nf][h], st[mf][nf], 0, 0, 0);
                __builtin_amdgcn_s_setprio(0);
            }

            const bool need_mask = (k0 + 63 > qw0);

            // fixed-base softmax: p = exp2(s); lane-local row-sum accumulate
            for (int nf = 0; nf < 2; ++nf) {
                const int qidx = qw0 + nf * 16 + lrow;
                if (need_mask) {
                    for (int mf = 0; mf < 4; mf++)
                        for (int r = 0; r < 4; r++) {
                            int key = k0 + mf * 16 + quad * 4 + r;
                            if (key > qidx) st[mf][nf][r] = -INFINITY;
                        }
                }
                float rsum = 0.f;
                for (int mf = 0; mf < 4; mf++) {
                    float p0 = exp2f(st[mf][nf][0]);
                    float p1 = exp2f(st[mf][nf][1]);
                    float p2 = exp2f(st[mf][nf][2]);
                    float p3 = exp2f(st[mf][nf][3]);
                    rsum += (p0 + p1) + (p2 + p3);
                    uint2 pk;
                    pk.x = cvtpk(p0, p1);
                    pk.y = cvtpk(p2, p3);
                    *(uint2*)&myPT[(nf * 16 + lrow) * LDK + mf * 16 + quad * 4] = pk;
                }
                lstat[nf] += rsum;   // cross-quad reduce deferred to epilogue
            }

            // O^T += V^T P^T (P read back from wave-private LDS; no barrier)
            for (int h = 0; h < 2; ++h) {
                bf16x8 vf[4], pf[2];
                for (int mf = 0; mf < 4; mf++)
                    vf[mf] = *(const bf16x8*)&sVt[(mf * 16 + lrow) * LDK + h * 32 + quad * 8];
                for (int nf = 0; nf < 2; nf++)
                    pf[nf] = *(const bf16x8*)&myPT[(nf * 16 + lrow) * LDK + h * 32 + quad * 8];
                __builtin_amdgcn_s_setprio(1);
                for (int mf = 0; mf < 4; mf++)
                    for (int nf = 0; nf < 2; nf++)
                        o[mf][nf] = __builtin_amdgcn_mfma_f32_16x16x32_bf16(vf[mf], pf[nf], o[mf][nf], 0, 0, 0);
                __builtin_amdgcn_s_setprio(0);
            }
        }

        // epilogue: lane holds O^T[d = mf*16+quad*4+r][query = qw0+nf*16+lrow]
        for (int nf = 0; nf < 2; ++nf) {
            float ls = lstat[nf];
            ls += __shfl_xor(ls, 16);
            ls += __shfl_xor(ls, 32);
            float inv = 1.f / ls;
            int s_ = qw0 + nf * 16 + lrow;
            size_t rowbase = (((size_t)(b_ * S_LEN + s_)) * HEADS + h_) * DK;
            for (int mf = 0; mf < 4; mf++) {
                int d0 = mf * 16 + quad * 4;
                uint2 pk;
                pk.x = pkbf(o[mf][nf][0] * inv, o[mf][nf][1] * inv);
                pk.y = pkbf(o[mf][nf][2] * inv, o[mf][nf][3] * inv);
                *(uint2*)&ctx[rowbase + d0] = pk;
            }
        }
    }
}

// ---------------------------------------------------------------------------
// FALLBACK path (ws_size < 104 MB): convert-in-staging GEMMs.
// ---------------------------------------------------------------------------
__global__ __launch_bounds__(256) void proj_fb_kernel(
    const float* __restrict__ q, const float* __restrict__ k, const float* __restrict__ v,
    const float* __restrict__ Wq, const float* __restrict__ Wk, const float* __restrict__ Wv,
    unsigned short* __restrict__ qh, unsigned short* __restrict__ kh, unsigned short* __restrict__ vh_t)
{
    const float* X; const float* W; unsigned short* Y;
    if (blockIdx.z == 0)      { X = q; W = Wq; Y = qh; }
    else if (blockIdx.z == 1) { X = k; W = Wk; Y = kh; }
    else                      { X = v; W = Wv; Y = vh_t; }

    __shared__ short sA[128 * LDK];
    __shared__ short sB[128 * LDK];
    const int t = threadIdx.x, lane = t & 63, wid = t >> 6;
    const int wrow = (wid >> 1) * 64, wcol = (wid & 1) * 64;
    const int m0 = blockIdx.x * 128, n0 = blockIdx.y * 128;
    const int lrow = lane & 15, quad = lane >> 4, lk = quad * 8;

    f32x4 acc[4][4];
    for (int i = 0; i < 4; i++) for (int j = 0; j < 4; j++) acc[i][j] = (f32x4){0.f, 0.f, 0.f, 0.f};

    for (int kb = 0; kb < DMODEL; kb += 64) {
        for (int it = 0; it < 8; ++it) {
            int idx = t + it * 256;
            int row = idx >> 4, c4 = (idx & 15) * 4;
            float4 fa = *(const float4*)&X[(size_t)(m0 + row) * DMODEL + kb + c4];
            float4 fb = *(const float4*)&W[(size_t)(n0 + row) * DMODEL + kb + c4];
            short4 sa = { (short)f2bf(fa.x), (short)f2bf(fa.y), (short)f2bf(fa.z), (short)f2bf(fa.w) };
            short4 sb = { (short)f2bf(fb.x), (short)f2bf(fb.y), (short)f2bf(fb.z), (short)f2bf(fb.w) };
            *(short4*)&sA[row * LDK + c4] = sa;
            *(short4*)&sB[row * LDK + c4] = sb;
        }
        __syncthreads();
        for (int kk = 0; kk < 64; kk += 32) {
            bf16x8 a[4], b[4];
            for (int i = 0; i < 4; i++) a[i] = *(const bf16x8*)&sA[(wrow + i * 16 + lrow) * LDK + kk + lk];
            for (int j = 0; j < 4; j++) b[j] = *(const bf16x8*)&sB[(wcol + j * 16 + lrow) * LDK + kk + lk];
            for (int i = 0; i < 4; i++)
                for (int j = 0; j < 4; j++)
                    acc[i][j] = __builtin_amdgcn_mfma_f32_16x16x32_bf16(a[i], b[j], acc[i][j], 0, 0, 0);
        }
        __syncthreads();
    }

    const float scale = (blockIdx.z == 0) ? QSCALE : 1.0f;
    for (int i = 0; i < 4; i++) {
        int grow = m0 + wrow + i * 16 + quad * 4;
        for (int j = 0; j < 4; j++) {
            int gcol = n0 + wcol + j * 16 + lrow;
            int h = gcol >> 6, d = gcol & 63;
            for (int r = 0; r < 4; r++) {
                int row = grow + r, b_ = row >> 11, s_ = row & 2047;
                unsigned short val = f2bf(acc[i][j][r] * scale);
                if (blockIdx.z == 2)
                    Y[(((size_t)(b_ * HEADS + h) * DK) + d) * S_LEN + s_] = val;
                else
                    Y[(((size_t)(b_ * HEADS + h) * S_LEN) + s_) * DK + d] = val;
            }
        }
    }
}

__global__ __launch_bounds__(256) void outproj_fb_kernel(
    const unsigned short* __restrict__ ctx, const float* __restrict__ Wo, float* __restrict__ out)
{
    __shared__ short sA[128 * LDK];
    __shared__ short sB[128 * LDK];
    const int t = threadIdx.x, lane = t & 63, wid = t >> 6;
    const int wrow = (wid >> 1) * 64, wcol = (wid & 1) * 64;
    const int m0 = blockIdx.x * 128, n0 = blockIdx.y * 128;
    const int lrow = lane & 15, quad = lane >> 4, lk = quad * 8;

    f32x4 acc[4][4];
    for (int i = 0; i < 4; i++) for (int j = 0; j < 4; j++) acc[i][j] = (f32x4){0.f, 0.f, 0.f, 0.f};

    for (int kb = 0; kb < DMODEL; kb += 64) {
        for (int it = 0; it < 4; ++it) {
            int idx = t + it * 256;
            int row = idx >> 3, c8 = (idx & 7) * 8;
            *(uint4*)&sA[row * LDK + c8] = *(const uint4*)&ctx[(size_t)(m0 + row) * DMODEL + kb + c8];
        }
        for (int it = 0; it < 8; ++it) {
            int idx = t + it * 256;
            int row = idx >> 4, c4 = (idx & 15) * 4;
            float4 fb = *(const float4*)&Wo[(size_t)(n0 + row) * DMODEL + kb + c4];
            short4 sb = { (short)f2bf(fb.x), (short)f2bf(fb.y), (short)f2bf(fb.z), (short)f2bf(fb.w) };
            *(short4*)&sB[row * LDK + c4] = sb;
        }
        __syncthreads();
        for (int kk = 0; kk < 64; kk += 32) {
            bf16x8 a[4], b[4];
            for (int i = 0; i < 4; i++) a[i] = *(const bf16x8*)&sA[(wrow + i * 16 + lrow) * LDK + kk + lk];
            for (int j = 0; j < 4; j++) b[j] = *(const bf16x8*)&sB[(wcol + j * 16 + lrow) * LDK + kk + lk];
            for (int i = 0; i < 4; i++)
                for (int j = 0; j < 4; j++)
                    acc[i][j] = __builtin_amdgcn_mfma_f32_16x16x32_bf16(a[i], b[j], acc[i][j], 0, 0, 0);
        }
        __syncthreads();
    }

    for (int i = 0; i < 4; i++) {
        int grow = m0 + wrow + i * 16 + quad * 4;
        for (int j = 0; j < 4; j++) {
            int gcol = n0 + wcol + j * 16 + lrow;
            for (int r = 0; r < 4; r++)
                out[(size_t)(grow + r) * DMODEL + gcol] = acc[i][j][r];
        }
    }
}

extern "C" void kernel_launch(void* const* d_in, const int* in_sizes, int n_in,
                              void* d_out, int out_size, void* d_ws, size_t ws_size,
                              hipStream_t stream)
{
    const float* q  = (const float*)d_in[0];
    const float* k  = (const float*)d_in[1];
    const float* v  = (const float*)d_in[2];
    // d_in[3] = causal mask — deterministic triu, applied analytically
    const float* Wq = (const float*)d_in[4];
    const float* Wk = (const float*)d_in[5];
    const float* Wv = (const float*)d_in[6];
    const float* Wo = (const float*)d_in[7];
    float* out = (float*)d_out;

    const size_t M8 = (size_t)8 * 1024 * 1024;
    const size_t need = (size_t)(52) * 1024 * 1024 * 2;  // 104 MB

    if (ws_size >= need) {
        unsigned short* qbf  = (unsigned short*)d_ws;
        unsigned short* kbf  = qbf + M8;
        unsigned short* vbf  = kbf + M8;
        unsigned short* wbf  = vbf + M8;
        unsigned short* qh   = wbf + (size_t)4 * 1024 * 1024;
        unsigned short* kh   = qh + M8;
        unsigned short* vh_t = kh + M8;
        unsigned short* ctx  = qbf;   // alias (qbf dead after proj)

        dim3 gCvt(4096, 7);
        convert_kernel<<<gCvt, 256, 0, stream>>>(q, k, v, Wq, Wk, Wv, Wo, qbf, kbf, vbf, wbf);

        dim3 gProj(64, 8, 3);
        proj_gemm_kernel<<<gProj, 256, 0, stream>>>(qbf, kbf, vbf, wbf, qh, kh, vh_t);

        dim3 gAttn(8, 64);   // paired q-tiles (qt, 15-qt): uniform 34 k-tiles/block
        attn_kernel<<<gAttn, 256, 0, stream>>>(qh, kh, vh_t, ctx);

        dim3 gOut(64, 8);
        outproj_gemm_kernel<<<gOut, 256, 0, stream>>>(ctx, wbf + (size_t)3 * 1024 * 1024, out);
    } else {
        unsigned short* qh   = (unsigned short*)d_ws;
        unsigned short* kh   = qh + M8;
        unsigned short* vh_t = kh + M8;
        unsigned short* ctx  = vh_t + M8;

        dim3 gProj(64, 8, 3);
        proj_fb_kernel<<<gProj, 256, 0, stream>>>(q, k, v, Wq, Wk, Wv, qh, kh, vh_t);

        dim3 gAttn(8, 64);
        attn_kernel<<<gAttn, 256, 0, stream>>>(qh, kh, vh_t, ctx);

        dim3 gOut(64, 8);
        outproj_fb_kernel<<<gOut, 256, 0, stream>>>(ctx, Wo, out);
    }
}

// Round 3
// 326.803 us; speedup vs baseline: 1.0964x; 1.0547x over previous
//
#include <hip/hip_runtime.h>
#include <hip/hip_bf16.h>
#include <stdint.h>

#define S_LEN 2048
#define DMODEL 1024
#define HEADS 16
#define DK 64
#define LDK 72   // padded stride for attn LDS tiles (144 B rows, 16B aligned)

// Q projection folds 1/sqrt(DK) * log2(e) so attention softmax is pure exp2.
#define QSCALE 0.18033688011112042f

typedef __attribute__((ext_vector_type(8))) short bf16x8;
typedef __attribute__((ext_vector_type(4))) float f32x4;

__device__ __forceinline__ unsigned short f2bf(float f) {
    union { float f; unsigned u; } c; c.f = f;
    unsigned u = c.u;
    u += 0x7fffu + ((u >> 16) & 1u);
    return (unsigned short)(u >> 16);
}

// pack two fp32 -> bf16x2 (RNE): 2x(bfe+add3) + v_perm
__device__ __forceinline__ unsigned pkbf(float a, float b) {
    union { float f; unsigned u; } ca, cb; ca.f = a; cb.f = b;
    unsigned ua = ca.u + (0x7fffu + ((ca.u >> 16) & 1u));
    unsigned ub = cb.u + (0x7fffu + ((cb.u >> 16) & 1u));
    return __builtin_amdgcn_perm(ub, ua, 0x07060302);  // [ub.hi16 : ua.hi16]
}

// single-instruction pack (gfx950): D.lo16 = bf16(a), D.hi16 = bf16(b), RNE.
__device__ __forceinline__ unsigned cvtpk(float a, float b) {
    unsigned r;
    asm("v_cvt_pk_bf16_f32 %0, %1, %2" : "=v"(r) : "v"(a), "v"(b));
    return r;
}

__device__ __forceinline__ void g2lds16(const unsigned short* g, unsigned short* l) {
    __builtin_amdgcn_global_load_lds((const __attribute__((address_space(1))) void*)g,
                                     (__attribute__((address_space(3))) void*)l, 16, 0, 0);
}

// ---------------------------------------------------------------------------
// fp32 -> bf16 convert pass. y selects tensor; 8 elems/thread.
// ---------------------------------------------------------------------------
__global__ __launch_bounds__(256) void convert_kernel(
    const float* __restrict__ q, const float* __restrict__ k, const float* __restrict__ v,
    const float* __restrict__ Wq, const float* __restrict__ Wk, const float* __restrict__ Wv,
    const float* __restrict__ Wo,
    unsigned short* __restrict__ qbf, unsigned short* __restrict__ kbf,
    unsigned short* __restrict__ vbf, unsigned short* __restrict__ wbf)
{
    const float* src; unsigned short* dst; int n8;
    const int y = blockIdx.y;
    if (y == 0)      { src = q;  dst = qbf;           n8 = 1048576; }
    else if (y == 1) { src = k;  dst = kbf;           n8 = 1048576; }
    else if (y == 2) { src = v;  dst = vbf;           n8 = 1048576; }
    else if (y == 3) { src = Wq; dst = wbf;           n8 = 131072; }
    else if (y == 4) { src = Wk; dst = wbf + 1048576; n8 = 131072; }
    else if (y == 5) { src = Wv; dst = wbf + 2097152; n8 = 131072; }
    else             { src = Wo; dst = wbf + 3145728; n8 = 131072; }
    int i = blockIdx.x * 256 + threadIdx.x;
    if (i >= n8) return;
    float4 f0 = ((const float4*)src)[(size_t)2 * i];
    float4 f1 = ((const float4*)src)[(size_t)2 * i + 1];
    union { unsigned u[4]; uint4 v; } o;
    o.u[0] = pkbf(f0.x, f0.y); o.u[1] = pkbf(f0.z, f0.w);
    o.u[2] = pkbf(f1.x, f1.y); o.u[3] = pkbf(f1.z, f1.w);
    *(uint4*)&dst[(size_t)8 * i] = o.v;
}

// ---------------------------------------------------------------------------
// R2 GEMM core: Y = A @ B^T, 256x128 tile, BK=64, 512 thr (8 waves, 4Mx2N).
// Counted-vmcnt double-buffer (T3/T4): stage(kt+1) issued, vmcnt(6) retires
// only kt's 6 loads -> raw s_barrier (no full drain!) -> 32 MFMA (T5 setprio)
// -> raw barrier. LDS XOR-swizzle c16^=(row&7) applied on pre-swizzled global
// SOURCE + swizzled ds_read (rule #21; global_load_lds dest stays linear).
// LDS: 2 x (A 256x64 + B 128x64) bf16 = 96 KB, 1 block/CU.
// ---------------------------------------------------------------------------
__device__ __forceinline__ void gemm_core_256x128(
    const unsigned short* __restrict__ Apanel,  // 256 rows x 1024, row-major
    const unsigned short* __restrict__ Bpanel,  // 128 rows x 1024, row-major
    unsigned short* sm,                         // 49152 shorts (96 KB)
    f32x4 acc[4][4])
{
    const int t    = threadIdx.x;
    const int lane = t & 63;
    const int w    = t >> 6;          // 0..7
    const int wm   = w >> 1;          // 0..3
    const int wn   = w & 1;           // 0..1
    const int lrow = lane & 15;
    const int quad = lane >> 4;

    // staging lane geometry: slot = i*512 + w*64 + lane; row = i*64+w*8+(lane>>3)
    const int l8   = lane >> 3;                 // row&7 within this lane's slot
    const int c16s = (lane & 7) ^ l8;           // inverse-swizzled 16B column
    const unsigned short* gA = Apanel + (size_t)(w * 8 + l8) * 1024 + c16s * 8;
    const unsigned short* gB = Bpanel + (size_t)(w * 8 + l8) * 1024 + c16s * 8;
    unsigned short* lA = sm + w * 512;          // + i*4096 per issue, wave-uniform
    unsigned short* lB = sm + 16384 + w * 512;

#define STAGE_KT(bufsel, kt) do {                                         \
        unsigned short* la = lA + (bufsel) * 24576;                       \
        unsigned short* lb = lB + (bufsel) * 24576;                       \
        const unsigned short* ga = gA + (kt) * 64;                        \
        const unsigned short* gb = gB + (kt) * 64;                        \
        g2lds16(ga,                        la);                           \
        g2lds16(ga + (size_t) 64 * 1024,   la + 4096);                    \
        g2lds16(ga + (size_t)128 * 1024,   la + 8192);                    \
        g2lds16(ga + (size_t)192 * 1024,   la + 12288);                   \
        g2lds16(gb,                        lb);                           \
        g2lds16(gb + (size_t) 64 * 1024,   lb + 4096);                    \
    } while (0)

    for (int i = 0; i < 4; i++) for (int j = 0; j < 4; j++) acc[i][j] = (f32x4){0.f, 0.f, 0.f, 0.f};

    STAGE_KT(0, 0);

#pragma unroll 1
    for (int kt = 0; kt < 16; ++kt) {
        const int buf = kt & 1;
        if (kt < 15) {
            STAGE_KT(buf ^ 1, kt + 1);
            asm volatile("s_waitcnt vmcnt(6)" ::: "memory");   // retire kt's 6 loads only
        } else {
            asm volatile("s_waitcnt vmcnt(0)" ::: "memory");   // tail: drain
        }
        __builtin_amdgcn_sched_barrier(0);
        __builtin_amdgcn_s_barrier();            // raw: no compiler vmcnt(0) drain
        __builtin_amdgcn_sched_barrier(0);

        const unsigned short* tA = sm + buf * 24576;
        const unsigned short* tB = sm + buf * 24576 + 16384;
        for (int kh = 0; kh < 2; ++kh) {
            const int cs = ((kh * 4 + quad) ^ (lrow & 7)) * 8;   // swizzled read col
            bf16x8 a[4], b[4];
            for (int mi = 0; mi < 4; mi++)
                a[mi] = *(const bf16x8*)&tA[(wm * 64 + mi * 16 + lrow) * 64 + cs];
            for (int nj = 0; nj < 4; nj++)
                b[nj] = *(const bf16x8*)&tB[(wn * 64 + nj * 16 + lrow) * 64 + cs];
            __builtin_amdgcn_s_setprio(1);
            for (int mi = 0; mi < 4; mi++)
                for (int nj = 0; nj < 4; nj++)
                    acc[mi][nj] = __builtin_amdgcn_mfma_f32_16x16x32_bf16(a[mi], b[nj], acc[mi][nj], 0, 0, 0);
            __builtin_amdgcn_s_setprio(0);
        }
        __builtin_amdgcn_sched_barrier(0);
        __builtin_amdgcn_s_barrier();            // protect buf reuse at kt+2
        __builtin_amdgcn_sched_barrier(0);
    }
#undef STAGE_KT
}

// Proj variant: z selects {q,k,v}; scatter epilogue to head layouts.
__global__ __launch_bounds__(512, 2) void proj_gemm_kernel(
    const unsigned short* __restrict__ qbf, const unsigned short* __restrict__ kbf,
    const unsigned short* __restrict__ vbf, const unsigned short* __restrict__ wbf,
    unsigned short* __restrict__ qh, unsigned short* __restrict__ kh,
    unsigned short* __restrict__ vh_t)
{
    const unsigned short* A; const unsigned short* Bm; unsigned short* Y;
    const int z = blockIdx.z;
    if (z == 0)      { A = qbf; Bm = wbf;           Y = qh;   }
    else if (z == 1) { A = kbf; Bm = wbf + 1048576; Y = kh;   }
    else             { A = vbf; Bm = wbf + 2097152; Y = vh_t; }

    __shared__ unsigned short sm[49152];   // 96 KB

    const int m0 = blockIdx.x * 256;
    const int n0 = blockIdx.y * 128;

    f32x4 acc[4][4];
    gemm_core_256x128(A + (size_t)m0 * 1024, Bm + (size_t)n0 * 1024, sm, acc);

    const int t = threadIdx.x, lane = t & 63;
    const int wm = (t >> 6) >> 1, wn = (t >> 6) & 1;
    const int lrow = lane & 15, quad = lane >> 4;
    const float scale = (z == 0) ? QSCALE : 1.0f;
    for (int i = 0; i < 4; i++) {
        int grow = m0 + wm * 64 + i * 16 + quad * 4;
        for (int j = 0; j < 4; j++) {
            int gcol = n0 + wn * 64 + j * 16 + lrow;
            int h = gcol >> 6, d = gcol & 63;
            for (int r = 0; r < 4; r++) {
                int row = grow + r;
                int b_ = row >> 11;
                int s_ = row & 2047;
                unsigned short val = f2bf(acc[i][j][r] * scale);
                if (z == 2)
                    Y[(((size_t)(b_ * HEADS + h) * DK) + d) * S_LEN + s_] = val;
                else
                    Y[(((size_t)(b_ * HEADS + h) * S_LEN) + s_) * DK + d] = val;
            }
        }
    }
}

// Out projection: out = ctx(bf16) @ Wo^T, fp32 row-major output.
__global__ __launch_bounds__(512, 2) void outproj_gemm_kernel(
    const unsigned short* __restrict__ ctx, const unsigned short* __restrict__ wobf,
    float* __restrict__ out)
{
    __shared__ unsigned short sm[49152];   // 96 KB

    const int m0 = blockIdx.x * 256;
    const int n0 = blockIdx.y * 128;

    f32x4 acc[4][4];
    gemm_core_256x128(ctx + (size_t)m0 * 1024, wobf + (size_t)n0 * 1024, sm, acc);

    const int t = threadIdx.x, lane = t & 63;
    const int wm = (t >> 6) >> 1, wn = (t >> 6) & 1;
    const int lrow = lane & 15, quad = lane >> 4;
    for (int i = 0; i < 4; i++) {
        int grow = m0 + wm * 64 + i * 16 + quad * 4;
        for (int j = 0; j < 4; j++) {
            int gcol = n0 + wn * 64 + j * 16 + lrow;
            for (int r = 0; r < 4; r++)
                out[(size_t)(grow + r) * DMODEL + gcol] = acc[i][j][r];
        }
    }
}

// ---------------------------------------------------------------------------
// Flash attention, causal — transposed-S, fixed-base exp2 softmax.
// PAIRED q-tiles (qt, 15-qt): uniform 34 k-tiles/block.
// R1: XCD-bijective swizzle + async-STAGE prefetch (T14) + v_cvt_pk_bf16_f32
//     P-pack + deferred row-sum reduce + setprio around MFMA (T5).
// ---------------------------------------------------------------------------
__global__ __launch_bounds__(256) void attn_kernel(
    const unsigned short* __restrict__ qh, const unsigned short* __restrict__ kh,
    const unsigned short* __restrict__ vh_t, unsigned short* __restrict__ ctx)
{
    __shared__ unsigned short sK[64 * LDK];
    __shared__ unsigned short sVt[64 * LDK];
    __shared__ unsigned short sPT[4][32 * LDK];   // per-wave [query][key]

    const int t    = threadIdx.x;
    const int lane = t & 63;
    const int wid  = t >> 6;
    // bijective XCD swizzle (nwg=512, 512%8==0): hw linear id -> work id so
    // all 8 q-blocks of one bh land on one XCD (K/V become L2-resident).
    const int lin  = (int)(blockIdx.y * gridDim.x + blockIdx.x);
    const int wlin = (lin & 7) * 64 + (lin >> 3);
    const int qx   = wlin & 7;
    const int bh   = wlin >> 3;
    const size_t base = (size_t)bh * S_LEN * DK;
    const int lrow = lane & 15;
    const int quad = lane >> 4;
    const int b_ = bh >> 4, h_ = bh & 15;
    unsigned short* myPT = &sPT[wid][0];

    // staging geometry (fixed per thread; two halves 32 rows apart)
    const int sr0 = t >> 3;            // 0..31
    const int sc0 = (t & 7) * 8;       // 0..56 shorts
    const unsigned short* gK = kh + base;     // [key][d]
    const unsigned short* gV = vh_t + base;   // [d][key]

    for (int pass = 0; pass < 2; ++pass) {
        const int qt = pass ? (15 - qx) : qx;
        const int q0 = qt * 128;
        const int qw0 = q0 + wid * 32;   // this wave's first query row

        // Q fragments -> registers (reused across all k-tiles of this pass)
        bf16x8 qreg[2][2];
        for (int nf = 0; nf < 2; ++nf)
            for (int h = 0; h < 2; ++h)
                qreg[nf][h] = *(const bf16x8*)&qh[base + (size_t)(qw0 + nf * 16 + lrow) * DK + h * 32 + quad * 8];

        f32x4 o[4][2];   // [mf(d)][nf(query)]
        for (int mf = 0; mf < 4; mf++) for (int nf = 0; nf < 2; nf++) o[mf][nf] = (f32x4){0.f, 0.f, 0.f, 0.f};
        float lstat[2] = { 0.f, 0.f };   // lane-local partial row sums

        const int ntiles = q0 / 64 + 2;   // keys < q0+128

        // prologue prefetch for kt=0 (T14: loads decoupled from LDS write)
        uint4 rK0 = *(const uint4*)&gK[(size_t)sr0 * DK + sc0];
        uint4 rK1 = *(const uint4*)&gK[(size_t)(sr0 + 32) * DK + sc0];
        uint4 rV0 = *(const uint4*)&gV[(size_t)sr0 * S_LEN + sc0];
        uint4 rV1 = *(const uint4*)&gV[(size_t)(sr0 + 32) * S_LEN + sc0];

        for (int kt = 0; kt < ntiles; ++kt) {
            const int k0 = kt * 64;
            __syncthreads();   // protect sK/sVt from previous tile's readers
            *(uint4*)&sK [sr0 * LDK + sc0]        = rK0;
            *(uint4*)&sK [(sr0 + 32) * LDK + sc0] = rK1;
            *(uint4*)&sVt[sr0 * LDK + sc0]        = rV0;
            *(uint4*)&sVt[(sr0 + 32) * LDK + sc0] = rV1;
            if (kt + 1 < ntiles) {   // issue next tile's loads; land under compute
                const int kn = k0 + 64;
                rK0 = *(const uint4*)&gK[(size_t)(kn + sr0) * DK + sc0];
                rK1 = *(const uint4*)&gK[(size_t)(kn + sr0 + 32) * DK + sc0];
                rV0 = *(const uint4*)&gV[(size_t)sr0 * S_LEN + kn + sc0];
                rV1 = *(const uint4*)&gV[(size_t)(sr0 + 32) * S_LEN + kn + sc0];
            }
            __syncthreads();

            if (k0 > qw0 + 31) continue;   // fully masked for this wave

            // S^T = K Q^T  (Q pre-scaled by 1/sqrt(DK)*log2e)
            f32x4 st[4][2];
            for (int mf = 0; mf < 4; mf++) for (int nf = 0; nf < 2; nf++) st[mf][nf] = (f32x4){0.f, 0.f, 0.f, 0.f};
            for (int h = 0; h < 2; ++h) {
                bf16x8 kf[4];
                for (int mf = 0; mf < 4; mf++)
                    kf[mf] = *(const bf16x8*)&sK[(mf * 16 + lrow) * LDK + h * 32 + quad * 8];
                __builtin_amdgcn_s_setprio(1);
                for (int mf = 0; mf < 4; mf++)
                    for (int nf = 0; nf < 2; nf++)
                        st[mf][nf] = __builtin_amdgcn_mfma_f32_16x16x32_bf16(kf[mf], qreg[nf][h], st[mf][nf], 0, 0, 0);
                __builtin_amdgcn_s_setprio(0);
            }

            const bool need_mask = (k0 + 63 > qw0);

            // fixed-base softmax: p = exp2(s); lane-local row-sum accumulate
            for (int nf = 0; nf < 2; ++nf) {
                const int qidx = qw0 + nf * 16 + lrow;
                if (need_mask) {
                    for (int mf = 0; mf < 4; mf++)
                        for (int r = 0; r < 4; r++) {
                            int key = k0 + mf * 16 + quad * 4 + r;
                            if (key > qidx) st[mf][nf][r] = -INFINITY;
                        }
                }
                float rsum = 0.f;
                for (int mf = 0; mf < 4; mf++) {
                    float p0 = exp2f(st[mf][nf][0]);
                    float p1 = exp2f(st[mf][nf][1]);
                    float p2 = exp2f(st[mf][nf][2]);
                    float p3 = exp2f(st[mf][nf][3]);
                    rsum += (p0 + p1) + (p2 + p3);
                    uint2 pk;
                    pk.x = cvtpk(p0, p1);
                    pk.y = cvtpk(p2, p3);
                    *(uint2*)&myPT[(nf * 16 + lrow) * LDK + mf * 16 + quad * 4] = pk;
                }
                lstat[nf] += rsum;   // cross-quad reduce deferred to epilogue
            }

            // O^T += V^T P^T (P read back from wave-private LDS; no barrier)
            for (int h = 0; h < 2; ++h) {
                bf16x8 vf[4], pf[2];
                for (int mf = 0; mf < 4; mf++)
                    vf[mf] = *(const bf16x8*)&sVt[(mf * 16 + lrow) * LDK + h * 32 + quad * 8];
                for (int nf = 0; nf < 2; nf++)
                    pf[nf] = *(const bf16x8*)&myPT[(nf * 16 + lrow) * LDK + h * 32 + quad * 8];
                __builtin_amdgcn_s_setprio(1);
                for (int mf = 0; mf < 4; mf++)
                    for (int nf = 0; nf < 2; nf++)
                        o[mf][nf] = __builtin_amdgcn_mfma_f32_16x16x32_bf16(vf[mf], pf[nf], o[mf][nf], 0, 0, 0);
                __builtin_amdgcn_s_setprio(0);
            }
        }

        // epilogue: lane holds O^T[d = mf*16+quad*4+r][query = qw0+nf*16+lrow]
        for (int nf = 0; nf < 2; ++nf) {
            float ls = lstat[nf];
            ls += __shfl_xor(ls, 16);
            ls += __shfl_xor(ls, 32);
            float inv = 1.f / ls;
            int s_ = qw0 + nf * 16 + lrow;
            size_t rowbase = (((size_t)(b_ * S_LEN + s_)) * HEADS + h_) * DK;
            for (int mf = 0; mf < 4; mf++) {
                int d0 = mf * 16 + quad * 4;
                uint2 pk;
                pk.x = pkbf(o[mf][nf][0] * inv, o[mf][nf][1] * inv);
                pk.y = pkbf(o[mf][nf][2] * inv, o[mf][nf][3] * inv);
                *(uint2*)&ctx[rowbase + d0] = pk;
            }
        }
    }
}

// ---------------------------------------------------------------------------
// FALLBACK path (ws_size < 104 MB): convert-in-staging GEMMs.
// ---------------------------------------------------------------------------
__global__ __launch_bounds__(256) void proj_fb_kernel(
    const float* __restrict__ q, const float* __restrict__ k, const float* __restrict__ v,
    const float* __restrict__ Wq, const float* __restrict__ Wk, const float* __restrict__ Wv,
    unsigned short* __restrict__ qh, unsigned short* __restrict__ kh, unsigned short* __restrict__ vh_t)
{
    const float* X; const float* W; unsigned short* Y;
    if (blockIdx.z == 0)      { X = q; W = Wq; Y = qh; }
    else if (blockIdx.z == 1) { X = k; W = Wk; Y = kh; }
    else                      { X = v; W = Wv; Y = vh_t; }

    __shared__ short sA[128 * LDK];
    __shared__ short sB[128 * LDK];
    const int t = threadIdx.x, lane = t & 63, wid = t >> 6;
    const int wrow = (wid >> 1) * 64, wcol = (wid & 1) * 64;
    const int m0 = blockIdx.x * 128, n0 = blockIdx.y * 128;
    const int lrow = lane & 15, quad = lane >> 4, lk = quad * 8;

    f32x4 acc[4][4];
    for (int i = 0; i < 4; i++) for (int j = 0; j < 4; j++) acc[i][j] = (f32x4){0.f, 0.f, 0.f, 0.f};

    for (int kb = 0; kb < DMODEL; kb += 64) {
        for (int it = 0; it < 8; ++it) {
            int idx = t + it * 256;
            int row = idx >> 4, c4 = (idx & 15) * 4;
            float4 fa = *(const float4*)&X[(size_t)(m0 + row) * DMODEL + kb + c4];
            float4 fb = *(const float4*)&W[(size_t)(n0 + row) * DMODEL + kb + c4];
            short4 sa = { (short)f2bf(fa.x), (short)f2bf(fa.y), (short)f2bf(fa.z), (short)f2bf(fa.w) };
            short4 sb = { (short)f2bf(fb.x), (short)f2bf(fb.y), (short)f2bf(fb.z), (short)f2bf(fb.w) };
            *(short4*)&sA[row * LDK + c4] = sa;
            *(short4*)&sB[row * LDK + c4] = sb;
        }
        __syncthreads();
        for (int kk = 0; kk < 64; kk += 32) {
            bf16x8 a[4], b[4];
            for (int i = 0; i < 4; i++) a[i] = *(const bf16x8*)&sA[(wrow + i * 16 + lrow) * LDK + kk + lk];
            for (int j = 0; j < 4; j++) b[j] = *(const bf16x8*)&sB[(wcol + j * 16 + lrow) * LDK + kk + lk];
            for (int i = 0; i < 4; i++)
                for (int j = 0; j < 4; j++)
                    acc[i][j] = __builtin_amdgcn_mfma_f32_16x16x32_bf16(a[i], b[j], acc[i][j], 0, 0, 0);
        }
        __syncthreads();
    }

    const float scale = (blockIdx.z == 0) ? QSCALE : 1.0f;
    for (int i = 0; i < 4; i++) {
        int grow = m0 + wrow + i * 16 + quad * 4;
        for (int j = 0; j < 4; j++) {
            int gcol = n0 + wcol + j * 16 + lrow;
            int h = gcol >> 6, d = gcol & 63;
            for (int r = 0; r < 4; r++) {
                int row = grow + r, b_ = row >> 11, s_ = row & 2047;
                unsigned short val = f2bf(acc[i][j][r] * scale);
                if (blockIdx.z == 2)
                    Y[(((size_t)(b_ * HEADS + h) * DK) + d) * S_LEN + s_] = val;
                else
                    Y[(((size_t)(b_ * HEADS + h) * S_LEN) + s_) * DK + d] = val;
            }
        }
    }
}

__global__ __launch_bounds__(256) void outproj_fb_kernel(
    const unsigned short* __restrict__ ctx, const float* __restrict__ Wo, float* __restrict__ out)
{
    __shared__ short sA[128 * LDK];
    __shared__ short sB[128 * LDK];
    const int t = threadIdx.x, lane = t & 63, wid = t >> 6;
    const int wrow = (wid >> 1) * 64, wcol = (wid & 1) * 64;
    const int m0 = blockIdx.x * 128, n0 = blockIdx.y * 128;
    const int lrow = lane & 15, quad = lane >> 4, lk = quad * 8;

    f32x4 acc[4][4];
    for (int i = 0; i < 4; i++) for (int j = 0; j < 4; j++) acc[i][j] = (f32x4){0.f, 0.f, 0.f, 0.f};

    for (int kb = 0; kb < DMODEL; kb += 64) {
        for (int it = 0; it < 4; ++it) {
            int idx = t + it * 256;
            int row = idx >> 3, c8 = (idx & 7) * 8;
            *(uint4*)&sA[row * LDK + c8] = *(const uint4*)&ctx[(size_t)(m0 + row) * DMODEL + kb + c8];
        }
        for (int it = 0; it < 8; ++it) {
            int idx = t + it * 256;
            int row = idx >> 4, c4 = (idx & 15) * 4;
            float4 fb = *(const float4*)&Wo[(size_t)(n0 + row) * DMODEL + kb + c4];
            short4 sb = { (short)f2bf(fb.x), (short)f2bf(fb.y), (short)f2bf(fb.z), (short)f2bf(fb.w) };
            *(short4*)&sB[row * LDK + c4] = sb;
        }
        __syncthreads();
        for (int kk = 0; kk < 64; kk += 32) {
            bf16x8 a[4], b[4];
            for (int i = 0; i < 4; i++) a[i] = *(const bf16x8*)&sA[(wrow + i * 16 + lrow) * LDK + kk + lk];
            for (int j = 0; j < 4; j++) b[j] = *(const bf16x8*)&sB[(wcol + j * 16 + lrow) * LDK + kk + lk];
            for (int i = 0; i < 4; i++)
                for (int j = 0; j < 4; j++)
                    acc[i][j] = __builtin_amdgcn_mfma_f32_16x16x32_bf16(a[i], b[j], acc[i][j], 0, 0, 0);
        }
        __syncthreads();
    }

    for (int i = 0; i < 4; i++) {
        int grow = m0 + wrow + i * 16 + quad * 4;
        for (int j = 0; j < 4; j++) {
            int gcol = n0 + wcol + j * 16 + lrow;
            for (int r = 0; r < 4; r++)
                out[(size_t)(grow + r) * DMODEL + gcol] = acc[i][j][r];
        }
    }
}

extern "C" void kernel_launch(void* const* d_in, const int* in_sizes, int n_in,
                              void* d_out, int out_size, void* d_ws, size_t ws_size,
                              hipStream_t stream)
{
    const float* q  = (const float*)d_in[0];
    const float* k  = (const float*)d_in[1];
    const float* v  = (const float*)d_in[2];
    // d_in[3] = causal mask — deterministic triu, applied analytically
    const float* Wq = (const float*)d_in[4];
    const float* Wk = (const float*)d_in[5];
    const float* Wv = (const float*)d_in[6];
    const float* Wo = (const float*)d_in[7];
    float* out = (float*)d_out;

    const size_t M8 = (size_t)8 * 1024 * 1024;
    const size_t need = (size_t)(52) * 1024 * 1024 * 2;  // 104 MB

    if (ws_size >= need) {
        unsigned short* qbf  = (unsigned short*)d_ws;
        unsigned short* kbf  = qbf + M8;
        unsigned short* vbf  = kbf + M8;
        unsigned short* wbf  = vbf + M8;
        unsigned short* qh   = wbf + (size_t)4 * 1024 * 1024;
        unsigned short* kh   = qh + M8;
        unsigned short* vh_t = kh + M8;
        unsigned short* ctx  = qbf;   // alias (qbf dead after proj)

        dim3 gCvt(4096, 7);
        convert_kernel<<<gCvt, 256, 0, stream>>>(q, k, v, Wq, Wk, Wv, Wo, qbf, kbf, vbf, wbf);

        dim3 gProj(32, 8, 3);   // 256x128 tiles: 768 blocks = exactly 3 rounds @1/CU
        proj_gemm_kernel<<<gProj, 512, 0, stream>>>(qbf, kbf, vbf, wbf, qh, kh, vh_t);

        dim3 gAttn(8, 64);   // paired q-tiles (qt, 15-qt): uniform 34 k-tiles/block
        attn_kernel<<<gAttn, 256, 0, stream>>>(qh, kh, vh_t, ctx);

        dim3 gOut(32, 8);    // 256 blocks = exactly 1 round
        outproj_gemm_kernel<<<gOut, 512, 0, stream>>>(ctx, wbf + (size_t)3 * 1024 * 1024, out);
    } else {
        unsigned short* qh   = (unsigned short*)d_ws;
        unsigned short* kh   = qh + M8;
        unsigned short* vh_t = kh + M8;
        unsigned short* ctx  = vh_t + M8;

        dim3 gProj(64, 8, 3);
        proj_fb_kernel<<<gProj, 256, 0, stream>>>(q, k, v, Wq, Wk, Wv, qh, kh, vh_t);

        dim3 gAttn(8, 64);
        attn_kernel<<<gAttn, 256, 0, stream>>>(qh, kh, vh_t, ctx);

        dim3 gOut(64, 8);
        outproj_fb_kernel<<<gOut, 256, 0, stream>>>(ctx, Wo, out);
    }
}